// Round 10
// baseline (110.949 us; speedup 1.0000x reference)
//
#include <hip/hip_runtime.h>

// out[b, t, w, c] = x[b, t + w - 9, c] (zero outside [0, T)), x: [32, 4096, 30] f32.
// Per (b,t) the 570-float output row = contiguous x span starting at (t-9)*30.
// History: wave-contiguous 4KB store clustering was the only win (64.6->56.2);
// length>4KB, NT, MLP, XCD-swizzle, LDS staging all null/worse. Untested
// variable: CONCURRENT STREAM COUNT. The 6.9TB/s fill runs at ~10% occupancy
// (~870 waves). This round: 512 blocks (8 waves/CU, 2048 waves), each wave
// sweeps a contiguous 146KB span via 143 back-to-back 1KB wave-stores.
// Side effect: x reuse becomes intra-wave L1-resident (~54 new B of x per 1KB
// written) -> fabric reads ~18MB total.

typedef float f32x4 __attribute__((ext_vector_type(4)));

constexpr int B   = 32;
constexpr int T   = 4096;           // power of 2
constexpr int C   = 30;
constexpr int PAD = 9;              // W/2
constexpr int ROW = 570;            // W*C floats per output row
constexpr int TC  = T * C;          // 122880 floats per batch of x
constexpr int PAIR_F4 = 285;        // float4 units per row-pair (1140 floats)
constexpr unsigned NPAIRS = (unsigned)B * (T / 2);   // 65536 row-pairs
constexpr unsigned TOTAL4 = NPAIRS * PAIR_F4;        // 18,662,400 float4 units
constexpr unsigned NCHUNK = TOTAL4 / 64;             // 291,600 1KB wave-chunks
constexpr unsigned NBLK   = 512;                     // 2 blocks/CU
constexpr unsigned NWAVE  = NBLK * 4;                // 2,048 waves
constexpr unsigned PER_WAVE = (NCHUNK + NWAVE - 1) / NWAVE;  // 143

__global__ __launch_bounds__(256)
void OverlapTimeWindowLayer_kernel(const float* __restrict__ x,
                                   f32x4* __restrict__ out) {
    const unsigned g    = (blockIdx.x * 256u + threadIdx.x) >> 6;  // wave id
    const int      lane = (int)(threadIdx.x & 63u);
    const unsigned c0   = g * PER_WAVE;      // this wave's first 1KB chunk

#pragma unroll 4
    for (unsigned k = 0; k < PER_WAVE; ++k) {
        const unsigned c = c0 + k;
        if (c >= NCHUNK) break;              // only the last ~9 waves hit this
        const unsigned v = c * 64u + (unsigned)lane;   // float4 unit index

        const unsigned p = v / PAIR_F4;            // row-pair (magic-mul div)
        const int u  = (int)(v - p * PAIR_F4);     // unit within pair [0,285)
        const int b  = (int)(p >> 11);             // / (T/2)
        const int tp = (int)(p & 2047);            // first row t = 2*tp
        const int base = (2 * tp - PAD) * C;       // x offset of row t
        const int e0 = 4 * u;                      // element offset within pair
        const float* xb = x + (unsigned)b * TC;

        // If element e >= ROW it belongs to row t+1: source -= (ROW - C).
        const int s0 = base + e0     - (e0     >= ROW ? (ROW - C) : 0);
        const int s1 = base + e0 + 2 - (e0 + 2 >= ROW ? (ROW - C) : 0);

        float2 lo = make_float2(0.0f, 0.0f);
        float2 hi = make_float2(0.0f, 0.0f);
        if (s0 >= 0 && s0 < TC) lo = *reinterpret_cast<const float2*>(xb + s0);
        if (s1 >= 0 && s1 < TC) hi = *reinterpret_cast<const float2*>(xb + s1);

        f32x4 val;
        val.x = lo.x; val.y = lo.y; val.z = hi.x; val.w = hi.y;
        out[v] = val;
    }
}

extern "C" void kernel_launch(void* const* d_in, const int* in_sizes, int n_in,
                              void* d_out, int out_size, void* d_ws, size_t ws_size,
                              hipStream_t stream) {
    const float* x = (const float*)d_in[0];
    f32x4* out = (f32x4*)d_out;
    OverlapTimeWindowLayer_kernel<<<NBLK, 256, 0, stream>>>(x, out);
}

// Round 11
// 92.648 us; speedup vs baseline: 1.1975x; 1.1975x over previous
//
#include <hip/hip_runtime.h>

// out[b, t, w, c] = x[b, t + w - 9, c] (zero outside [0, T)), x: [32, 4096, 30] f32.
// Per (b,t) the 570-float output row = contiguous x span starting at (t-9)*30.
// Ladder: wave-contiguous 4KB clustering 64.6->56.2us (R6); length>4KB, NT,
// MLP, XCD-swizzle, LDS staging all null; R10 low-occupancy WITHOUT latency
// hiding regressed (110us, loads stall the store stream). This round: R10's
// fill-like stream structure (2048 waves, 144 contiguous 1KB chunks each)
// + depth-4 SOFTWARE PIPELINE with static register slots: prefetch chunk
// k+4's operands while storing chunk k, so stores run back-to-back and load
// latency hides under 4 chunks (~2900 cyc lead >> 900 cyc HBM).

typedef float f32x4 __attribute__((ext_vector_type(4)));

constexpr int B   = 32;
constexpr int T   = 4096;           // power of 2
constexpr int C   = 30;
constexpr int PAD = 9;              // W/2
constexpr int ROW = 570;            // W*C floats per output row
constexpr int TC  = T * C;          // 122880 floats per batch of x
constexpr int PAIR_F4 = 285;        // float4 units per row-pair
constexpr unsigned NPAIRS = (unsigned)B * (T / 2);   // 65536 row-pairs
constexpr unsigned TOTAL4 = NPAIRS * PAIR_F4;        // 18,662,400 float4 units
constexpr unsigned NCHUNK = TOTAL4 / 64;             // 291,600 1KB wave-chunks
constexpr unsigned NBLK   = 512;                     // 2 blocks/CU, 8 waves/CU
constexpr unsigned NWAVE  = NBLK * 4;                // 2,048 waves
constexpr unsigned PER_WAVE = 144;                   // 4-divisible cover (guarded)

// Compute addresses + issue guarded loads for chunk CC into slot J.
// Address math uses a clamped chunk id so OOB tail waves never form wild
// pointers; the store guard uses the real CC.
#define PREP(J, CC)                                                          \
  {                                                                          \
    const unsigned cA = (CC) < NCHUNK ? (CC) : (NCHUNK - 1u);                \
    v##J = cA * 64u + (unsigned)lane;                                        \
    const unsigned p = v##J / (unsigned)PAIR_F4;      /* magic-mul div */    \
    const int u  = (int)(v##J - p * (unsigned)PAIR_F4);                      \
    const int bb = (int)(p >> 11);                    /* / (T/2) */          \
    const int tp = (int)(p & 2047u);                                         \
    const int base = (2 * tp - PAD) * C;                                     \
    const int e0 = 4 * u;                                                    \
    const float* xb = xg + (unsigned)bb * (unsigned)TC;                      \
    const int s0 = base + e0     - (e0     >= ROW ? (ROW - C) : 0);          \
    const int s1 = base + e0 + 2 - (e0 + 2 >= ROW ? (ROW - C) : 0);          \
    lo##J = make_float2(0.0f, 0.0f);                                         \
    hi##J = make_float2(0.0f, 0.0f);                                         \
    if (s0 >= 0 && s0 < TC) lo##J = *reinterpret_cast<const float2*>(xb + s0);\
    if (s1 >= 0 && s1 < TC) hi##J = *reinterpret_cast<const float2*>(xb + s1);\
  }

#define EMIT(J, CC)                                                          \
  if ((CC) < NCHUNK) {                                                       \
    f32x4 val;                                                               \
    val.x = lo##J.x; val.y = lo##J.y; val.z = hi##J.x; val.w = hi##J.y;      \
    out[v##J] = val;                                                         \
  }

__global__ __launch_bounds__(256)
void OverlapTimeWindowLayer_kernel(const float* __restrict__ xg,
                                   f32x4* __restrict__ out) {
    const unsigned wave = (blockIdx.x * 256u + threadIdx.x) >> 6;
    const int      lane = (int)(threadIdx.x & 63u);
    const unsigned c0   = wave * PER_WAVE;   // contiguous 144KB region per wave

    unsigned v0_, v1_, v2_, v3_;
    float2 lo0_, lo1_, lo2_, lo3_, hi0_, hi1_, hi2_, hi3_;
    // Rename to match macro token pasting (slot names: v0_, lo0_, hi0_ ...).
#define v0 v0_
#define v1 v1_
#define v2 v2_
#define v3 v3_
#define lo0 lo0_
#define lo1 lo1_
#define lo2 lo2_
#define lo3 lo3_
#define hi0 hi0_
#define hi1 hi1_
#define hi2 hi2_
#define hi3 hi3_

    // Prologue: prefetch chunks c0 .. c0+3.
    PREP(0, c0 + 0u)
    PREP(1, c0 + 1u)
    PREP(2, c0 + 2u)
    PREP(3, c0 + 3u)

    for (unsigned kk = 0; kk < PER_WAVE; kk += 4) {
        // Store slot j (chunk c0+kk+j), then refill it with chunk c0+kk+j+4.
        // Final iteration's PREPs target guarded-out chunks (pure VALU, no
        // loads land, stores skipped) — negligible.
        EMIT(0, c0 + kk + 0u) PREP(0, c0 + kk + 4u)
        EMIT(1, c0 + kk + 1u) PREP(1, c0 + kk + 5u)
        EMIT(2, c0 + kk + 2u) PREP(2, c0 + kk + 6u)
        EMIT(3, c0 + kk + 3u) PREP(3, c0 + kk + 7u)
    }
}

extern "C" void kernel_launch(void* const* d_in, const int* in_sizes, int n_in,
                              void* d_out, int out_size, void* d_ws, size_t ws_size,
                              hipStream_t stream) {
    const float* x = (const float*)d_in[0];
    f32x4* out = (f32x4*)d_out;
    OverlapTimeWindowLayer_kernel<<<NBLK, 256, 0, stream>>>(x, out);
}

// Round 12
// 56.699 us; speedup vs baseline: 1.9568x; 1.6341x over previous
//
#include <hip/hip_runtime.h>

// out[b, t, w, c] = x[b, t + w - 9, c] (zero outside [0, T)), x: [32, 4096, 30] f32.
// Per (b,t) the 570-float output row = contiguous x span starting at (t-9)*30.
// Best so far: R6 (full occupancy, wave-contiguous 4KB store clusters,
// 3 vmem/unit) = 56.2us. This round isolates VMEM INSTRUCTION COUNT: the
// 4 floats of almost every output float4 unit are CONTIGUOUS in x (8B-aligned),
// so use ONE dwordx4 load + one store (2 vmem/unit instead of 3). Only the
// row-straddling unit (u==142) and batch-edge units need the two-float2 path.

typedef float f32x4 __attribute__((ext_vector_type(4)));
struct __attribute__((aligned(8))) f4a { float v[4]; };  // align-8 16B load

constexpr int B   = 32;
constexpr int T   = 4096;           // power of 2
constexpr int C   = 30;
constexpr int PAD = 9;              // W/2
constexpr int ROW = 570;            // W*C floats per output row
constexpr int TC  = T * C;          // 122880 floats per batch of x
constexpr int PAIR_F4 = 285;        // float4 units per row-pair (1140 floats)
constexpr unsigned NPAIRS = (unsigned)B * (T / 2);   // 65536 row-pairs
constexpr unsigned TOTAL4 = NPAIRS * PAIR_F4;        // 18,662,400 float4 units
constexpr int UNROLL = 4;           // wave covers 256 units = 4KB sequential

__global__ __launch_bounds__(256)
void OverlapTimeWindowLayer_kernel(const float* __restrict__ x,
                                   f32x4* __restrict__ out) {
    const unsigned g    = blockIdx.x * 256u + threadIdx.x;
    const unsigned wave = g >> 6;
    const int      lane = (int)(g & 63u);
    const unsigned vbase = wave * 256u + (unsigned)lane;  // unit for k=0
#pragma unroll
    for (int k = 0; k < UNROLL; ++k) {
        const unsigned v = vbase + (unsigned)(64 * k);  // wave-contiguous 1KB each
        const unsigned p = v / PAIR_F4;            // row-pair (magic-mul div)
        const int u  = (int)(v - p * PAIR_F4);     // unit within pair [0,285)
        const int b  = (int)(p >> 11);             // / (T/2)
        const int tp = (int)(p & 2047);            // first row t = 2*tp
        const int base = (2 * tp - PAD) * C;       // x offset of row t
        const int e0 = 4 * u;                      // element offset within pair
        const float* xb = x + (unsigned)b * TC;

        // Contiguous source start (whole unit in one row unless u==142).
        const int sA = base + e0 - (e0 >= ROW ? (ROW - C) : 0);

        f32x4 val;
        if (u != 142 && sA >= 0 && sA + 4 <= TC) {
            // Fast path: ONE 16B load (8B-aligned; sA ≡ 2 mod 4).
            const f4a tmp = *reinterpret_cast<const f4a*>(xb + sA);
            val.x = tmp.v[0]; val.y = tmp.v[1]; val.z = tmp.v[2]; val.w = tmp.v[3];
        } else {
            // Straddle / batch-edge path: two guarded float2 loads.
            const int s0 = base + e0     - (e0     >= ROW ? (ROW - C) : 0);
            const int s1 = base + e0 + 2 - (e0 + 2 >= ROW ? (ROW - C) : 0);
            float2 lo = make_float2(0.0f, 0.0f);
            float2 hi = make_float2(0.0f, 0.0f);
            if (s0 >= 0 && s0 < TC) lo = *reinterpret_cast<const float2*>(xb + s0);
            if (s1 >= 0 && s1 < TC) hi = *reinterpret_cast<const float2*>(xb + s1);
            val.x = lo.x; val.y = lo.y; val.z = hi.x; val.w = hi.y;
        }
        out[v] = val;
    }
}

extern "C" void kernel_launch(void* const* d_in, const int* in_sizes, int n_in,
                              void* d_out, int out_size, void* d_ws, size_t ws_size,
                              hipStream_t stream) {
    const float* x = (const float*)d_in[0];
    f32x4* out = (f32x4*)d_out;
    const int block = 256;
    const unsigned grid = TOTAL4 / (256u * (unsigned)UNROLL / 4u) / 256u * 256u; // keep exact:
    (void)grid;
    const unsigned nwg = TOTAL4 / (64u * (unsigned)UNROLL) / 4u;  // 18,225 blocks
    OverlapTimeWindowLayer_kernel<<<nwg, block, 0, stream>>>(x, out);
}